// Round 1
// baseline (322.734 us; speedup 1.0000x reference)
//
#include <hip/hip_runtime.h>
#include <hip/hip_bf16.h>
#include <stdint.h>

#define DIMK 256
#define DIMV 384
#define NSEQ 1024
#define NHEAD 6

typedef __attribute__((ext_vector_type(8))) short short8;
typedef __attribute__((ext_vector_type(4))) float floatx4;

__device__ __forceinline__ unsigned short f2b(float f){
  unsigned int x = __float_as_uint(f);
  return (unsigned short)((x + 0x7fffu + ((x >> 16) & 1u)) >> 16);
}
__device__ __forceinline__ unsigned int pack2(float a, float b){
  return (unsigned int)f2b(a) | ((unsigned int)f2b(b) << 16);
}

// transpose + convert: W [256][384] f32 -> Wt [384][256] bf16 (both weights)
__global__ void conv_w_kernel(const float* __restrict__ WQ, const float* __restrict__ WK,
                              unsigned short* __restrict__ wqt, unsigned short* __restrict__ wkt){
  int i = blockIdx.x * 256 + threadIdx.x;      // 0 .. 196607
  const float* W; unsigned short* O; int idx;
  if (i < 98304){ W = WQ; O = wqt; idx = i; }
  else          { W = WK; O = wkt; idx = i - 98304; }
  int n = idx >> 8;          // 0..383
  int k = idx & 255;         // 0..255
  O[idx] = f2b(W[(size_t)k * 384 + n]);
}

// Y[M=8192][384] = bf16(X[8192][256]) @ bf16(W)[256][384] + bias   (f32 out)
// grid (128, 4), 256 threads. BM=64, BN=96, BK=64.
__global__ __launch_bounds__(256) void proj_kernel(const float* __restrict__ X,
    const unsigned short* __restrict__ Wt,   // [384][256] bf16 (pre-transposed)
    const float* __restrict__ bias,
    float* __restrict__ Y)
{
  __shared__ uint4 lA[512];       // [kc 0..7][row 0..63], 16B chunk = 8 bf16 along k
  __shared__ uint4 lB[864];       // [n 0..95][kc 0..8 (1 chunk pad)]
  int t = threadIdx.x;
  int lane = t & 63, wave = t >> 6;
  int wm = wave >> 1, wn = wave & 1;           // 2x2 wave grid
  int rb = blockIdx.x * 64;
  int nb = blockIdx.y * 96;
  floatx4 acc[2][3];
  #pragma unroll
  for (int mi = 0; mi < 2; ++mi)
    #pragma unroll
    for (int ni = 0; ni < 3; ++ni) acc[mi][ni] = (floatx4){0.f, 0.f, 0.f, 0.f};

  for (int it = 0; it < 4; ++it){
    int k0 = it * 64;
    // stage A: 512 chunks, f32 -> bf16 in registers
    #pragma unroll
    for (int i = 0; i < 2; ++i){
      int c = t + i * 256;
      int kc = c >> 6, row = c & 63;
      const float* src = X + (size_t)(rb + row) * DIMK + k0 + kc * 8;
      float4 f0 = *(const float4*)src;
      float4 f1 = *(const float4*)(src + 4);
      uint4 w;
      w.x = pack2(f0.x, f0.y); w.y = pack2(f0.z, f0.w);
      w.z = pack2(f1.x, f1.y); w.w = pack2(f1.z, f1.w);
      lA[c] = w;
    }
    // stage B: 768 chunks (bf16 source, contiguous 16B)
    #pragma unroll
    for (int i = 0; i < 3; ++i){
      int c = t + i * 256;
      int n = c >> 3, kc = c & 7;
      uint4 v = *(const uint4*)(Wt + (size_t)(nb + n) * DIMK + k0 + kc * 8);
      lB[n * 9 + kc] = v;
    }
    __syncthreads();
    #pragma unroll
    for (int kk = 0; kk < 2; ++kk){
      int kc  = kk * 4 + (lane >> 4);
      int r16 = lane & 15;
      short8 af[2], bf[3];
      #pragma unroll
      for (int mi = 0; mi < 2; ++mi)
        af[mi] = *(const short8*)&lA[kc * 64 + wm * 32 + mi * 16 + r16];
      #pragma unroll
      for (int ni = 0; ni < 3; ++ni)
        bf[ni] = *(const short8*)&lB[(wn * 48 + ni * 16 + r16) * 9 + kc];
      #pragma unroll
      for (int mi = 0; mi < 2; ++mi)
        #pragma unroll
        for (int ni = 0; ni < 3; ++ni)
          acc[mi][ni] = __builtin_amdgcn_mfma_f32_16x16x32_bf16(af[mi], bf[ni], acc[mi][ni], 0, 0, 0);
    }
    __syncthreads();
  }
  // epilogue: C/D layout col=lane&15, row=(lane>>4)*4+q (m89-verified)
  int r16 = lane & 15, rq = lane >> 4;
  #pragma unroll
  for (int ni = 0; ni < 3; ++ni){
    int col = nb + wn * 48 + ni * 16 + r16;
    float bv = bias[col];
    #pragma unroll
    for (int mi = 0; mi < 2; ++mi){
      #pragma unroll
      for (int q = 0; q < 4; ++q){
        int row = rb + wm * 32 + mi * 16 + rq * 4 + q;
        Y[(size_t)row * DIMV + col] = acc[mi][ni][q] + bv;
      }
    }
  }
}

// One workgroup per (b,n) row; 6 waves = 1 per head.
// Build unmasked index list from A, gather k rows, wave-reduce dots,
// sparsemax via bisection + exact tau, zero-fill + scatter output.
__global__ __launch_bounds__(384) void attn_kernel(const float* __restrict__ qb,
    const float* __restrict__ kb, const float* __restrict__ A, float* __restrict__ out)
{
  __shared__ int   idxs[1024];
  __shared__ float sv[NHEAD][1024];
  __shared__ int   Msh;
  int r = blockIdx.x;            // b*1024 + n
  int b = r >> 10;
  int t = threadIdx.x;
  int lane = t & 63, wave = t >> 6;

  float ql = qb[(size_t)r * DIMV + wave * 64 + lane];

  if (wave == 0){
    const float* arow = A + (size_t)r * NSEQ;
    float av[16];
    #pragma unroll
    for (int c = 0; c < 16; ++c) av[c] = arow[c * 64 + lane];   // 16 loads in flight
    int base = 0;
    #pragma unroll
    for (int c = 0; c < 16; ++c){
      bool on = av[c] > 0.5f;
      unsigned long long m = __ballot(on);
      int pre = __popcll(m & ((1ull << lane) - 1ull));
      if (on) idxs[base + pre] = c * 64 + lane;
      base += __popcll(m);
    }
    if (lane == 0) Msh = base;
  }
  __syncthreads();
  int M = Msh;

  const float* kbase = kb + (size_t)b * NSEQ * DIMV + wave * 64 + lane;
  const float scale = 0.05103103630798288f;    // 1/sqrt(384)
  float maxv = -3e38f;
  int j = 0;
  for (; j + 4 <= M; j += 4){
    int i0 = idxs[j], i1 = idxs[j+1], i2 = idxs[j+2], i3 = idxs[j+3];
    float p0 = ql * kbase[(size_t)i0 * DIMV];
    float p1 = ql * kbase[(size_t)i1 * DIMV];
    float p2 = ql * kbase[(size_t)i2 * DIMV];
    float p3 = ql * kbase[(size_t)i3 * DIMV];
    #pragma unroll
    for (int o = 1; o < 64; o <<= 1){
      p0 += __shfl_xor(p0, o); p1 += __shfl_xor(p1, o);
      p2 += __shfl_xor(p2, o); p3 += __shfl_xor(p3, o);
    }
    p0 *= scale; p1 *= scale; p2 *= scale; p3 *= scale;
    if (lane == 0){
      sv[wave][j] = p0; sv[wave][j+1] = p1; sv[wave][j+2] = p2; sv[wave][j+3] = p3;
    }
    maxv = fmaxf(maxv, fmaxf(fmaxf(p0, p1), fmaxf(p2, p3)));
  }
  for (; j < M; ++j){
    float p = ql * kbase[(size_t)idxs[j] * DIMV];
    #pragma unroll
    for (int o = 1; o < 64; o <<= 1) p += __shfl_xor(p, o);
    p *= scale;
    if (lane == 0) sv[wave][j] = p;
    maxv = fmaxf(maxv, p);
  }
  __syncthreads();   // make lane0's sv writes visible to whole wave (uniform barrier)

  // bisection for tau on [maxv-1, maxv): f(tau)=sum(max(z-tau,0)) is decreasing, f(lo)>=1>f(hi)
  float lo = maxv - 1.0f, hi = maxv;
  for (int bi = 0; bi < 28; ++bi){
    float mid = 0.5f * (lo + hi);
    float s = 0.f;
    for (int jj = lane; jj < M; jj += 64) s += fmaxf(sv[wave][jj] - mid, 0.f);
    #pragma unroll
    for (int o = 1; o < 64; o <<= 1) s += __shfl_xor(s, o);
    if (s >= 1.f) lo = mid; else hi = mid;
  }
  // exact tau from the (stable) support set
  float ssum = 0.f; int cnt = 0;
  for (int jj = lane; jj < M; jj += 64){
    float z = sv[wave][jj];
    if (z > lo){ ssum += z; cnt++; }
  }
  #pragma unroll
  for (int o = 1; o < 64; o <<= 1){ ssum += __shfl_xor(ssum, o); cnt += __shfl_xor(cnt, o); }
  float tau = (ssum - 1.0f) / (float)cnt;

  // output: zero-fill this head's 1024-float zone, then scatter nonzeros
  float* orow = out + (size_t)r * (NHEAD * NSEQ) + wave * NSEQ;
  float4 z4 = make_float4(0.f, 0.f, 0.f, 0.f);
  #pragma unroll
  for (int u = 0; u < 4; ++u) ((float4*)orow)[u * 64 + lane] = z4;
  asm volatile("s_waitcnt vmcnt(0)" ::: "memory");   // order zero-fill before scatter
  for (int jj = lane; jj < M; jj += 64){
    float p = sv[wave][jj] - tau;
    if (p > 0.f) orow[idxs[jj]] = p;
  }
}

extern "C" void kernel_launch(void* const* d_in, const int* in_sizes, int n_in,
                              void* d_out, int out_size, void* d_ws, size_t ws_size,
                              hipStream_t stream) {
  const float* Q  = (const float*)d_in[0];
  const float* V  = (const float*)d_in[1];
  const float* A  = (const float*)d_in[2];
  const float* WQ = (const float*)d_in[3];
  const float* bQ = (const float*)d_in[4];
  const float* WK = (const float*)d_in[5];
  const float* bK = (const float*)d_in[6];
  float* out = (float*)d_out;

  char* ws = (char*)d_ws;
  const size_t QK_BYTES = (size_t)8192 * 384 * 4;       // 12.58 MB each
  float* qbuf = (float*)ws;
  float* kbuf = (float*)(ws + QK_BYTES);
  unsigned short* wqt = (unsigned short*)(ws + 2 * QK_BYTES);
  unsigned short* wkt = wqt + 98304;
  (void)in_sizes; (void)n_in; (void)out_size; (void)ws_size;

  conv_w_kernel<<<768, 256, 0, stream>>>(WQ, WK, wqt, wkt);
  proj_kernel<<<dim3(128, 4), 256, 0, stream>>>(Q, wqt, bQ, qbuf);
  proj_kernel<<<dim3(128, 4), 256, 0, stream>>>(V, wkt, bK, kbuf);
  attn_kernel<<<8192, 384, 0, stream>>>(qbuf, kbuf, A, out);
}